// Round 8
// baseline (527.254 us; speedup 1.0000x reference)
//
#include <hip/hip_runtime.h>
#include <hip/hip_bf16.h>

#define BATCH 16384
#define HDIM  1024
#define K1    2048

typedef __attribute__((ext_vector_type(4))) float f32x4;
typedef __attribute__((ext_vector_type(8))) short short8;

__device__ __forceinline__ unsigned short f2bf(float f) {
  union { float f; unsigned u; } v; v.f = f;
  unsigned r = v.u + 0x7FFFu + ((v.u >> 16) & 1u);
  return (unsigned short)(r >> 16);
}
__device__ __forceinline__ float bf2f(unsigned short h) {
  union { unsigned u; float f; } v; v.u = ((unsigned)h) << 16; return v.f;
}
__device__ __forceinline__ float sigmoidf_(float x) {
  return 1.0f / (1.0f + __builtin_amdgcn_exp2f(x * -1.4426950408889634f));
}
__device__ __forceinline__ float tanhf_(float x) {
  float xc = fminf(fmaxf(x, -8.0f), 8.0f);
  float e = __builtin_amdgcn_exp2f(xc * 2.8853900817779268f);
  return (e - 1.0f) / (e + 1.0f);
}
__device__ __forceinline__ void async16(const void* g, void* l) {
  __builtin_amdgcn_global_load_lds((const __attribute__((address_space(1))) void*)g,
                                   (__attribute__((address_space(3))) void*)l, 16, 0, 0);
}
template <int N> __device__ __forceinline__ void vmwait() {
  if constexpr (N == 5)      asm volatile("s_waitcnt vmcnt(5)" ::: "memory");
  else if constexpr (N == 4) asm volatile("s_waitcnt vmcnt(4)" ::: "memory");
  else if constexpr (N == 3) asm volatile("s_waitcnt vmcnt(3)" ::: "memory");
  else if constexpr (N == 2) asm volatile("s_waitcnt vmcnt(2)" ::: "memory");
  else                       asm volatile("s_waitcnt vmcnt(0)" ::: "memory");
}

// ---- conversion pass: U = [x|y] bf16 (16384 x 2048) ----
__global__ void k_convU(const float* __restrict__ x, const float* __restrict__ y,
                        unsigned short* __restrict__ U) {
  const int total = BATCH * (HDIM / 4);
  for (int q = blockIdx.x * blockDim.x + threadIdx.x; q < total;
       q += gridDim.x * blockDim.x) {
    int b = q >> 8;
    int c = (q & 255) << 2;
    float4 xv = *(const float4*)(x + (long)b * HDIM + c);
    float4 yv = *(const float4*)(y + (long)b * HDIM + c);
    uint2 xo, yo;
    xo.x = (unsigned)f2bf(xv.x) | ((unsigned)f2bf(xv.y) << 16);
    xo.y = (unsigned)f2bf(xv.z) | ((unsigned)f2bf(xv.w) << 16);
    yo.x = (unsigned)f2bf(yv.x) | ((unsigned)f2bf(yv.y) << 16);
    yo.y = (unsigned)f2bf(yv.z) | ((unsigned)f2bf(yv.w) << 16);
    *(uint2*)(U + (long)b * K1 + c) = xo;
    *(uint2*)(U + (long)b * K1 + HDIM + c) = yo;
  }
}

// ---- conversion: permuted Wcat (3072 x 2048) + Wzcat (1024 x 2048) ----
// Wcat n' = bn*192 + w*48 + c*16 + i -> chunk c of h = bn*64 + w*16 + i
// Wzcat row n = [Wz[n] | W_ih[2H+n]]  (z_new@Wz^T + i_z fused, K=2048)
__global__ void k_convW(const float* __restrict__ Wih, const float* __restrict__ Whh,
                        const float* __restrict__ Wz,
                        unsigned short* __restrict__ Wcat, unsigned short* __restrict__ Wzcat) {
  const int stride = gridDim.x * blockDim.x;
  const int totalW = 3072 * (K1 / 4);
  for (int q = blockIdx.x * blockDim.x + threadIdx.x; q < totalW; q += stride) {
    int np = q >> 9;
    int kb = (q & 511) << 2;
    int bn = np / 192; int r = np - bn * 192;
    int w = r / 48; int r2 = r - w * 48;
    int c = r2 >> 4, i = r2 & 15;
    int h = bn * 64 + w * 16 + i;
    float4 v;
    if (kb < HDIM) {
      int row = (c == 0) ? h : (c == 1) ? (HDIM + h) : (3 * HDIM + h);
      v = *(const float4*)(Wih + (long)row * HDIM + kb);
    } else {
      int row = (c == 0) ? h : (c == 1) ? (HDIM + h) : (2 * HDIM + h);
      v = *(const float4*)(Whh + (long)row * HDIM + (kb - HDIM));
    }
    uint2 o;
    o.x = (unsigned)f2bf(v.x) | ((unsigned)f2bf(v.y) << 16);
    o.y = (unsigned)f2bf(v.z) | ((unsigned)f2bf(v.w) << 16);
    *(uint2*)(Wcat + (long)np * K1 + kb) = o;
  }
  const int totalZ = HDIM * (K1 / 4);
  for (int q = blockIdx.x * blockDim.x + threadIdx.x; q < totalZ; q += stride) {
    int n = q >> 9;
    int kb = (q & 511) << 2;
    float4 v = (kb < HDIM) ? *(const float4*)(Wz + (long)n * HDIM + kb)
                           : *(const float4*)(Wih + (long)(2 * HDIM + n) * HDIM + (kb - HDIM));
    uint2 o;
    o.x = (unsigned)f2bf(v.x) | ((unsigned)f2bf(v.y) << 16);
    o.y = (unsigned)f2bf(v.z) | ((unsigned)f2bf(v.w) << 16);
    *(uint2*)(Wzcat + (long)n * K1 + kb) = o;
  }
}

// ---- GEMM core: 128-row x (NF*64)-col tile, 4 waves (1M x 4N), 256 thr ----
// Cross-block overlap is the point: small blocks -> 3-4 INDEPENDENT blocks
// per CU; when one block's waves sit in barrier/VALU/load phases, other
// blocks' waves feed the MFMA pipes (m114 co-issue).
// A staged global_load_lds -> 4 x 8KB LDS buffers, stage distance 2
// (buffer kt&3 re-staged at iter kt+2, two barriers later -> skew-safe).
// B direct global->reg double-buffered (L2-resident panels).
// Counted vmcnt(NF+2) pre-barrier: forces stage(kt+1)+B(kt) complete,
// leaves stage(kt+2)+B(kt+1) in flight. LDS XOR-swizzle (slot=rA&7) on A
// via inverse-swizzled global source; 0 bank conflicts.
#define STAGEA(TT)                                                        \
  do {                                                                    \
    char* bb_ = lds + ((TT) & 3) * 8192;                                  \
    const unsigned short *sa_, *sb_;                                      \
    if ((TT) < KSPLIT) { sa_ = pA1a + (long)(TT) * 32; sb_ = pA1b + (long)(TT) * 32; } \
    else { sa_ = pA2a + (long)((TT) - KSPLIT) * 32; sb_ = pA2b + (long)((TT) - KSPLIT) * 32; } \
    async16(sa_, bb_ + t16);                                              \
    async16(sb_, bb_ + 4096 + t16);                                       \
  } while (0)

#define ITER(BFC, BFN, KT, VMN, DOB, DOS)                                 \
  do {                                                                    \
    const char* Ab_ = lds + ((KT) & 3) * 8192;                            \
    _Pragma("unroll") for (int m_ = 0; m_ < 4; ++m_)                      \
      af[m_] = *(const short8*)(Ab_ + offA[m_]);                          \
    if (DOB) {                                                            \
      _Pragma("unroll") for (int n_ = 0; n_ < NF; ++n_)                   \
        BFN[n_] = *(const short8*)(pB[n_] + (long)((KT) + 1) * 32);       \
    }                                                                     \
    if (DOS) STAGEA((KT) + 2);                                            \
    vmwait<VMN>();                                                        \
    __builtin_amdgcn_s_barrier();                                         \
    __builtin_amdgcn_sched_barrier(0);                                    \
    __builtin_amdgcn_s_setprio(1);                                        \
    _Pragma("unroll") for (int m_ = 0; m_ < 4; ++m_)                      \
      _Pragma("unroll") for (int n_ = 0; n_ < NF; ++n_)                   \
        acc[m_][n_] = __builtin_amdgcn_mfma_f32_16x16x32_bf16(            \
            af[m_], BFC[n_], acc[m_][n_], 0, 0, 0);                       \
    __builtin_amdgcn_s_setprio(0);                                        \
    _Pragma("unroll") for (int m_ = 0; m_ < 4; ++m_)                      \
      af[m_] = *(const short8*)(Ab_ + offA[4 + m_]);                      \
    __builtin_amdgcn_s_setprio(1);                                        \
    _Pragma("unroll") for (int m_ = 0; m_ < 4; ++m_)                      \
      _Pragma("unroll") for (int n_ = 0; n_ < NF; ++n_)                   \
        acc[4 + m_][n_] = __builtin_amdgcn_mfma_f32_16x16x32_bf16(        \
            af[m_], BFC[n_], acc[4 + m_][n_], 0, 0, 0);                   \
    __builtin_amdgcn_s_setprio(0);                                        \
  } while (0)

template <int NF, int KSPLIT>
__device__ __forceinline__ void gemm_core(
    const unsigned short* __restrict__ A1, int strA1,
    const unsigned short* __restrict__ A2, int strA2,
    const unsigned short* __restrict__ Bg,
    long arow0, long brow0, char* lds, f32x4 acc[8][NF]) {
  constexpr int NT = 64;
  constexpr int VMS = NF + 2;   // steady
  constexpr int VMT = NF;       // iter NT-2 (only B issued)
  const int t = threadIdx.x, lane = t & 63, wv = t >> 6;
  const int wn = wv & 3;
  const int rA = lane & 15;
  const int cphys = ((lane >> 4) << 4) ^ (((rA >> 1) & 3) << 4);
  const int t16 = t * 16;
  const int s0 = t16 ^ (((t16 >> 7) & 3) << 4);  // inverse-swizzled source
  const int r0 = s0 >> 6, c0e = (s0 & 63) >> 1;
  const unsigned short* pA1a = A1 + (arow0 + r0) * (long)strA1 + c0e;
  const unsigned short* pA1b = A1 + (arow0 + r0 + 64) * (long)strA1 + c0e;
  const unsigned short* pA2a = A2 + (arow0 + r0) * (long)strA2 + c0e;
  const unsigned short* pA2b = A2 + (arow0 + r0 + 64) * (long)strA2 + c0e;
  const int bcol = (lane >> 4) << 3;
  const unsigned short* pB[NF];
#pragma unroll
  for (int n = 0; n < NF; ++n)
    pB[n] = Bg + (brow0 + wn * (NF * 16) + n * 16 + rA) * (long)K1 + bcol;
  int offA[8];
#pragma unroll
  for (int m = 0; m < 8; ++m)
    offA[m] = (m * 16 + rA) * 64 + cphys;

  // prologue: stage A-tiles 0,1; load B frags(0)
  STAGEA(0);
  STAGEA(1);
  short8 bfA[NF], bfB[NF];
#pragma unroll
  for (int n = 0; n < NF; ++n) bfA[n] = *(const short8*)(pB[n]);
  vmwait<VMS>();  // tile0 landed; tile1 + B0 may be in flight (B0 waited by dep)
  __builtin_amdgcn_s_barrier();

  short8 af[4];
#pragma unroll 1
  for (int kt = 0; kt < NT - 2; kt += 2) {
    ITER(bfA, bfB, kt, VMS, 1, 1);
    ITER(bfB, bfA, kt + 1, VMS, 1, 1);
  }
  ITER(bfA, bfB, NT - 2, VMT, 1, 0);
  ITER(bfB, bfA, NT - 1, 0, 0, 0);
}

// ---- phase 1: fused U@Wcat^T + LEM elementwise (128x192 tiles) ----
__global__ __launch_bounds__(256, 3) void k_gemm1(
    const unsigned short* __restrict__ U, const unsigned short* __restrict__ Wcat,
    const float* __restrict__ z, const float* __restrict__ dtp,
    const float* __restrict__ bih, const float* __restrict__ bhh,
    const float* __restrict__ Wdt, const float* __restrict__ bdt,
    float* __restrict__ out, unsigned short* __restrict__ znb,
    unsigned short* __restrict__ sbb) {
  __shared__ char lds[32768];
  const int bid = blockIdx.x;
  const int sid = (bid & 7) * 256 + (bid >> 3);  // XCD-bijective (2048 % 8 == 0)
  const int bm = sid >> 4, bn = sid & 15;
  f32x4 acc[8][3];
#pragma unroll
  for (int m = 0; m < 8; ++m)
#pragma unroll
    for (int n = 0; n < 3; ++n) acc[m][n] = (f32x4)(0.0f);

  gemm_core<3, 64>(U, K1, U, K1, Wcat, (long)bm * 128, (long)bn * 192, lds, acc);

  const int t = threadIdx.x, lane = t & 63, wv = t >> 6;
  const int wn = wv & 3;
  const int rA = lane & 15, q4 = (lane >> 4) << 2;
  const int h = bn * 64 + wn * 16 + rA;
  const int rowbase = bm * 128;
  const float bi0 = bih[h] + bhh[h];
  const float bi1 = bih[HDIM + h] + bhh[HDIM + h];
  const float bi2 = bih[3 * HDIM + h] + bhh[2 * HDIM + h];
  const float wdt0 = Wdt[0], wdt1 = Wdt[1], bdt0 = bdt[0], bdt1 = bdt[1];
#pragma unroll
  for (int m = 0; m < 8; ++m) {
#pragma unroll
    for (int j = 0; j < 4; ++j) {
      const int b = rowbase + m * 16 + q4 + j;
      const long idx = (long)b * HDIM + h;
      const float dv = dtp[b];
      const float s1 = sigmoidf_(dv * wdt0 + bdt0);
      const float s2 = sigmoidf_(dv * wdt1 + bdt1);
      const float sbar = s1 * sigmoidf_(acc[m][0][j] + bi0);
      const float s = s2 * sigmoidf_(acc[m][1][j] + bi1);
      const float zt = tanhf_(acc[m][2][j] + bi2);
      const float znew = (1.0f - s) * z[idx] + s * zt;
      out[(long)BATCH * HDIM + idx] = znew;  // z_new output (f32)
      znb[idx] = f2bf(znew);                  // A-left-half for phase 2
      sbb[idx] = f2bf(sbar);
    }
  }
}

// ---- phase 2: [z_new|x]@[Wz|Wih_2H]^T + y_new epilogue (128x128 tiles) ----
__global__ __launch_bounds__(256, 4) void k_gemm2(
    const unsigned short* __restrict__ Zn, const unsigned short* __restrict__ U,
    const unsigned short* __restrict__ Wzcat, const unsigned short* __restrict__ sbb,
    const float* __restrict__ yin, const float* __restrict__ bz,
    float* __restrict__ out) {
  __shared__ char lds[32768];
  const int bid = blockIdx.x;
  const int sid = (bid & 7) * 128 + (bid >> 3);  // 1024 % 8 == 0
  const int bm = sid >> 3, bn = sid & 7;
  f32x4 acc[8][2];
#pragma unroll
  for (int m = 0; m < 8; ++m)
#pragma unroll
    for (int n = 0; n < 2; ++n) acc[m][n] = (f32x4)(0.0f);

  // A: kt<32 -> Znb (stride 1024), kt>=32 -> x half of U (stride 2048)
  gemm_core<2, 32>(Zn, HDIM, U, K1, Wzcat, (long)bm * 128, (long)bn * 128, lds, acc);

  const int t = threadIdx.x, lane = t & 63, wv = t >> 6;
  const int wn = wv & 3;
  const int rA = lane & 15, q4 = (lane >> 4) << 2;
  const int rowbase = bm * 128;
#pragma unroll
  for (int n = 0; n < 2; ++n) {
    const int hc = bn * 128 + wn * 32 + n * 16 + rA;
    const float bzv = bz[hc];
#pragma unroll
    for (int m = 0; m < 8; ++m) {
#pragma unroll
      for (int j = 0; j < 4; ++j) {
        const int b = rowbase + m * 16 + q4 + j;
        const long idx = (long)b * HDIM + hc;
        const float tv = tanhf_(acc[m][n][j] + bzv);
        const float sb = bf2f(sbb[idx]);
        out[idx] = (1.0f - sb) * yin[idx] + sb * tv;  // y_new
      }
    }
  }
}

extern "C" void kernel_launch(void* const* d_in, const int* in_sizes, int n_in,
                              void* d_out, int out_size, void* d_ws, size_t ws_size,
                              hipStream_t stream) {
  const float* x   = (const float*)d_in[0];
  const float* y   = (const float*)d_in[1];
  const float* z   = (const float*)d_in[2];
  const float* dtp = (const float*)d_in[3];
  const float* Wih = (const float*)d_in[4];
  const float* bih = (const float*)d_in[5];
  const float* Whh = (const float*)d_in[6];
  const float* bhh = (const float*)d_in[7];
  const float* Wz  = (const float*)d_in[8];
  const float* bz  = (const float*)d_in[9];
  const float* Wdt = (const float*)d_in[10];
  const float* bdt = (const float*)d_in[11];

  char* ws = (char*)d_ws;
  unsigned short* U     = (unsigned short*)(ws);              // 67,108,864 B
  unsigned short* Wcat  = (unsigned short*)(ws + 67108864);   // 12,582,912 B
  unsigned short* Wzcat = (unsigned short*)(ws + 79691776);   //  4,194,304 B
  unsigned short* Znb   = (unsigned short*)(ws + 83886080);   // 33,554,432 B
  unsigned short* Sbb   = (unsigned short*)(ws + 117440512);  // 33,554,432 B -> 150,994,944 B
  float* out = (float*)d_out;

  k_convU<<<2048, 256, 0, stream>>>(x, y, U);
  k_convW<<<2048, 256, 0, stream>>>(Wih, Whh, Wz, Wcat, Wzcat);
  k_gemm1<<<2048, 256, 0, stream>>>(U, Wcat, z, dtp, bih, bhh, Wdt, bdt, out, Znb, Sbb);
  k_gemm2<<<1024, 256, 0, stream>>>(Znb, U, Wzcat, Sbb, y, bz, out);
}

// Round 9
// 379.808 us; speedup vs baseline: 1.3882x; 1.3882x over previous
//
#include <hip/hip_runtime.h>
#include <hip/hip_bf16.h>

#define BATCH 16384
#define HDIM  1024
#define K1    2048

typedef __attribute__((ext_vector_type(4))) float f32x4;
typedef __attribute__((ext_vector_type(8))) short short8;

__device__ __forceinline__ unsigned short f2bf(float f) {
  union { float f; unsigned u; } v; v.f = f;
  unsigned r = v.u + 0x7FFFu + ((v.u >> 16) & 1u);
  return (unsigned short)(r >> 16);
}
__device__ __forceinline__ float bf2f(unsigned short h) {
  union { unsigned u; float f; } v; v.u = ((unsigned)h) << 16; return v.f;
}
__device__ __forceinline__ float sigmoidf_(float x) {
  return 1.0f / (1.0f + __builtin_amdgcn_exp2f(x * -1.4426950408889634f));
}
__device__ __forceinline__ float tanhf_(float x) {
  float xc = fminf(fmaxf(x, -8.0f), 8.0f);
  float e = __builtin_amdgcn_exp2f(xc * 2.8853900817779268f);
  return (e - 1.0f) / (e + 1.0f);
}
__device__ __forceinline__ void async16(const void* g, void* l) {
  __builtin_amdgcn_global_load_lds((const __attribute__((address_space(1))) void*)g,
                                   (__attribute__((address_space(3))) void*)l, 16, 0, 0);
}

// ---- conversion pass: U = [x|y] bf16 (16384 x 2048) ----
__global__ void k_convU(const float* __restrict__ x, const float* __restrict__ y,
                        unsigned short* __restrict__ U) {
  const int total = BATCH * (HDIM / 4);
  for (int q = blockIdx.x * blockDim.x + threadIdx.x; q < total;
       q += gridDim.x * blockDim.x) {
    int b = q >> 8;
    int c = (q & 255) << 2;
    float4 xv = *(const float4*)(x + (long)b * HDIM + c);
    float4 yv = *(const float4*)(y + (long)b * HDIM + c);
    uint2 xo, yo;
    xo.x = (unsigned)f2bf(xv.x) | ((unsigned)f2bf(xv.y) << 16);
    xo.y = (unsigned)f2bf(xv.z) | ((unsigned)f2bf(xv.w) << 16);
    yo.x = (unsigned)f2bf(yv.x) | ((unsigned)f2bf(yv.y) << 16);
    yo.y = (unsigned)f2bf(yv.z) | ((unsigned)f2bf(yv.w) << 16);
    *(uint2*)(U + (long)b * K1 + c) = xo;
    *(uint2*)(U + (long)b * K1 + HDIM + c) = yo;
  }
}

// ---- conversion: permuted Wcat (3072 x 2048) + Wzcat (1024 x 2048) ----
// Wcat n' = bn*192 + w*48 + c*16 + i -> chunk c of h = bn*64 + w*16 + i
// Wzcat row n = [Wz[n] | W_ih[2H+n]]  (z_new@Wz^T + i_z fused, K=2048)
__global__ void k_convW(const float* __restrict__ Wih, const float* __restrict__ Whh,
                        const float* __restrict__ Wz,
                        unsigned short* __restrict__ Wcat, unsigned short* __restrict__ Wzcat) {
  const int stride = gridDim.x * blockDim.x;
  const int totalW = 3072 * (K1 / 4);
  for (int q = blockIdx.x * blockDim.x + threadIdx.x; q < totalW; q += stride) {
    int np = q >> 9;
    int kb = (q & 511) << 2;
    int bn = np / 192; int r = np - bn * 192;
    int w = r / 48; int r2 = r - w * 48;
    int c = r2 >> 4, i = r2 & 15;
    int h = bn * 64 + w * 16 + i;
    float4 v;
    if (kb < HDIM) {
      int row = (c == 0) ? h : (c == 1) ? (HDIM + h) : (3 * HDIM + h);
      v = *(const float4*)(Wih + (long)row * HDIM + kb);
    } else {
      int row = (c == 0) ? h : (c == 1) ? (HDIM + h) : (2 * HDIM + h);
      v = *(const float4*)(Whh + (long)row * HDIM + (kb - HDIM));
    }
    uint2 o;
    o.x = (unsigned)f2bf(v.x) | ((unsigned)f2bf(v.y) << 16);
    o.y = (unsigned)f2bf(v.z) | ((unsigned)f2bf(v.w) << 16);
    *(uint2*)(Wcat + (long)np * K1 + kb) = o;
  }
  const int totalZ = HDIM * (K1 / 4);
  for (int q = blockIdx.x * blockDim.x + threadIdx.x; q < totalZ; q += stride) {
    int n = q >> 9;
    int kb = (q & 511) << 2;
    float4 v = (kb < HDIM) ? *(const float4*)(Wz + (long)n * HDIM + kb)
                           : *(const float4*)(Wih + (long)(2 * HDIM + n) * HDIM + (kb - HDIM));
    uint2 o;
    o.x = (unsigned)f2bf(v.x) | ((unsigned)f2bf(v.y) << 16);
    o.y = (unsigned)f2bf(v.z) | ((unsigned)f2bf(v.w) << 16);
    *(uint2*)(Wzcat + (long)n * K1 + kb) = o;
  }
}

// ---- GEMM core: 256 x (NB*64... actually NB*16*4=NB*64-col? no: NB frags
// per wave x 4 wn waves) tile = 256 rows x NB*64 cols. R4 slip schedule:
// 8 waves (2M x 4N), 4 LDS K-tile buffers, staging distance 3,
// ONE barrier per kt, 8xNB MFMA cluster per barrier. Per kt:
//   {8+NB ds_read; stage A+B (kt+3); s_waitcnt vmcnt(cnt) lgkmcnt(0);
//    s_barrier; sched_barrier; setprio(1); 8*NB MFMA; setprio(0)}
// Counted vmcnt forces stage(kt+1) complete, leaves stage(kt+2),(kt+3) in
// flight. B staged wave-uniformly when 12KB (waves 0-3: 2 loads, 4-7: 1).
// LDS XOR-swizzle slot=row&7 via inverse-swizzled global source; 0 conflicts.
template <int NB, int KSPLIT, bool BSPLIT>
__device__ __forceinline__ void gemm_core(
    const unsigned short* __restrict__ A1, int strA1,
    const unsigned short* __restrict__ A2, int strA2,
    const unsigned short* __restrict__ Bg,
    long arow0, long brow0, char* lds, f32x4 acc[8][NB]) {
  constexpr int NT = 64;
  constexpr int BBYTES = NB * 4096;
  char* ldsA = lds;
  char* ldsB = lds + 65536;
  const int t = threadIdx.x, lane = t & 63, wv = t >> 6;
  const int wm = wv >> 2, wn = wv & 3;
  const int rA = lane & 15;
  const int cphys = ((lane >> 4) << 4) ^ (((rA >> 1) & 3) << 4);
  const int t16 = t * 16;
  const bool blo = (t < 256);

  // A staging (16KB tile = 2 loads/thread), inverse-swizzled source
  const int sA = t16 ^ (((t16 >> 7) & 3) << 4);
  const int rA0 = sA >> 6, cA0 = (sA & 63) >> 1;
  const unsigned short* pA1a = A1 + (arow0 + rA0) * (long)strA1 + cA0;
  const unsigned short* pA1b = A1 + (arow0 + rA0 + 128) * (long)strA1 + cA0;
  const unsigned short* pA2a = A2 + (arow0 + rA0) * (long)strA2 + cA0;
  const unsigned short* pA2b = A2 + (arow0 + rA0 + 128) * (long)strA2 + cA0;

  // B staging: BSPLIT (12KB): lo waves 2 loads (L=t16, t16+4096), hi waves 1
  // (L=t16+4096 i.e. 8192+(t-256)*16). !BSPLIT (8KB): 1 load (L=t16).
  const int Lb0 = BSPLIT ? (blo ? t16 : t16 + 4096) : t16;
  const int Lb1 = t16 + 4096;
  const int sB0 = Lb0 ^ (((Lb0 >> 7) & 3) << 4);
  const int sB1 = Lb1 ^ (((Lb1 >> 7) & 3) << 4);
  const unsigned short* pBg0 = Bg + (brow0 + (sB0 >> 6)) * (long)K1 + ((sB0 & 63) >> 1);
  const unsigned short* pBg1 = Bg + (brow0 + (sB1 >> 6)) * (long)K1 + ((sB1 & 63) >> 1);

  int offA[8], offB[NB];
#pragma unroll
  for (int m = 0; m < 8; ++m)
    offA[m] = (wm * 128 + m * 16 + rA) * 64 + cphys;
#pragma unroll
  for (int n = 0; n < NB; ++n)
    offB[n] = (wn * (NB * 16) + n * 16 + rA) * 64 + cphys;

#define STAGEA_(TT)                                                       \
  do {                                                                    \
    char* ab_ = ldsA + ((TT) & 3) * 16384;                                \
    if ((TT) < KSPLIT) {                                                  \
      async16(pA1a + (long)(TT) * 32, ab_ + t16);                         \
      async16(pA1b + (long)(TT) * 32, ab_ + 8192 + t16);                  \
    } else {                                                              \
      async16(pA2a + (long)((TT) - KSPLIT) * 32, ab_ + t16);              \
      async16(pA2b + (long)((TT) - KSPLIT) * 32, ab_ + 8192 + t16);       \
    }                                                                     \
  } while (0)
#define STAGEB_(TT)                                                       \
  do {                                                                    \
    char* bb_ = ldsB + ((TT) & 3) * BBYTES;                               \
    async16(pBg0 + (long)(TT) * 32, bb_ + Lb0);                           \
    if (BSPLIT && blo) async16(pBg1 + (long)(TT) * 32, bb_ + Lb1);        \
  } while (0)
#define WSTEADY_                                                          \
  do {                                                                    \
    if (BSPLIT) {                                                         \
      if (blo) asm volatile("s_waitcnt vmcnt(8) lgkmcnt(0)" ::: "memory");\
      else     asm volatile("s_waitcnt vmcnt(6) lgkmcnt(0)" ::: "memory");\
    } else     asm volatile("s_waitcnt vmcnt(6) lgkmcnt(0)" ::: "memory");\
  } while (0)
#define WTAIL1_                                                           \
  do {                                                                    \
    if (BSPLIT) {                                                         \
      if (blo) asm volatile("s_waitcnt vmcnt(4) lgkmcnt(0)" ::: "memory");\
      else     asm volatile("s_waitcnt vmcnt(3) lgkmcnt(0)" ::: "memory");\
    } else     asm volatile("s_waitcnt vmcnt(3) lgkmcnt(0)" ::: "memory");\
  } while (0)
#define WTAIL0_ asm volatile("s_waitcnt vmcnt(0) lgkmcnt(0)" ::: "memory")
#define WLAST_  asm volatile("s_waitcnt lgkmcnt(0)" ::: "memory")
#define ITER_(KT, WAITSEL, DOSTG)                                         \
  do {                                                                    \
    const char* Ab_ = ldsA + ((KT) & 3) * 16384;                          \
    const char* Bb_ = ldsB + ((KT) & 3) * BBYTES;                         \
    short8 af_[8]; short8 bf_[NB];                                        \
    _Pragma("unroll") for (int m_ = 0; m_ < 8; ++m_)                      \
      af_[m_] = *(const short8*)(Ab_ + offA[m_]);                         \
    _Pragma("unroll") for (int n_ = 0; n_ < NB; ++n_)                     \
      bf_[n_] = *(const short8*)(Bb_ + offB[n_]);                         \
    if (DOSTG) { STAGEA_((KT) + 3); STAGEB_((KT) + 3); }                  \
    WAITSEL;                                                              \
    __builtin_amdgcn_s_barrier();                                         \
    __builtin_amdgcn_sched_barrier(0);                                    \
    __builtin_amdgcn_s_setprio(1);                                        \
    _Pragma("unroll") for (int m_ = 0; m_ < 8; ++m_)                      \
      _Pragma("unroll") for (int n_ = 0; n_ < NB; ++n_)                   \
        acc[m_][n_] = __builtin_amdgcn_mfma_f32_16x16x32_bf16(            \
            af_[m_], bf_[n_], acc[m_][n_], 0, 0, 0);                      \
    __builtin_amdgcn_s_setprio(0);                                        \
  } while (0)

  // prologue: stage K-tiles 0,1,2; force tile 0 landed
  STAGEA_(0); STAGEB_(0);
  STAGEA_(1); STAGEB_(1);
  STAGEA_(2); STAGEB_(2);
  WSTEADY_;
  __builtin_amdgcn_s_barrier();

#pragma unroll 1
  for (int kt = 0; kt < NT - 3; ++kt) ITER_(kt, WSTEADY_, true);
  ITER_(NT - 3, WTAIL1_, false);
  ITER_(NT - 2, WTAIL0_, false);
  ITER_(NT - 1, WLAST_, false);
#undef STAGEA_
#undef STAGEB_
#undef WSTEADY_
#undef WTAIL1_
#undef WTAIL0_
#undef WLAST_
#undef ITER_
}

// ---- phase 1: fused U@Wcat^T + LEM elementwise (256x192 tiles) ----
__global__ __launch_bounds__(512, 2) void k_gemm1(
    const unsigned short* __restrict__ U, const unsigned short* __restrict__ Wcat,
    const float* __restrict__ z, const float* __restrict__ dtp,
    const float* __restrict__ bih, const float* __restrict__ bhh,
    const float* __restrict__ Wdt, const float* __restrict__ bdt,
    float* __restrict__ out, unsigned short* __restrict__ znb,
    unsigned short* __restrict__ sbb) {
  __shared__ char lds[114688];  // 64KB A + 48KB B
  const int bid = blockIdx.x;
  const int sid = (bid & 7) * 128 + (bid >> 3);  // 1024 % 8 == 0
  const int bm = sid >> 4, bn = sid & 15;
  f32x4 acc[8][3];
#pragma unroll
  for (int m = 0; m < 8; ++m)
#pragma unroll
    for (int n = 0; n < 3; ++n) acc[m][n] = (f32x4)(0.0f);

  gemm_core<3, 64, true>(U, K1, U, K1, Wcat, (long)bm * 256, (long)bn * 192, lds, acc);

  const int t = threadIdx.x, lane = t & 63, wv = t >> 6;
  const int wm = wv >> 2, wn = wv & 3;
  const int rA = lane & 15, q4 = (lane >> 4) << 2;
  const int h = bn * 64 + wn * 16 + rA;
  const int rowbase = bm * 256 + wm * 128;
  const float bi0 = bih[h] + bhh[h];
  const float bi1 = bih[HDIM + h] + bhh[HDIM + h];
  const float bi2 = bih[3 * HDIM + h] + bhh[2 * HDIM + h];
  const float wdt0 = Wdt[0], wdt1 = Wdt[1], bdt0 = bdt[0], bdt1 = bdt[1];
#pragma unroll
  for (int m = 0; m < 8; ++m) {
#pragma unroll
    for (int j = 0; j < 4; ++j) {
      const int b = rowbase + m * 16 + q4 + j;
      const long idx = (long)b * HDIM + h;
      const float dv = dtp[b];
      const float s1 = sigmoidf_(dv * wdt0 + bdt0);
      const float s2 = sigmoidf_(dv * wdt1 + bdt1);
      const float sbar = s1 * sigmoidf_(acc[m][0][j] + bi0);
      const float s = s2 * sigmoidf_(acc[m][1][j] + bi1);
      const float zt = tanhf_(acc[m][2][j] + bi2);
      const float znew = (1.0f - s) * z[idx] + s * zt;
      out[(long)BATCH * HDIM + idx] = znew;  // z_new output (f32)
      znb[idx] = f2bf(znew);                  // A-left-half for phase 2
      sbb[idx] = f2bf(sbar);
    }
  }
}

// ---- phase 2: [z_new|x]@[Wz|Wih_2H]^T + y_new epilogue (256x128 tiles) ----
__global__ __launch_bounds__(512, 2) void k_gemm2(
    const unsigned short* __restrict__ Zn, const unsigned short* __restrict__ U,
    const unsigned short* __restrict__ Wzcat, const unsigned short* __restrict__ sbb,
    const float* __restrict__ yin, const float* __restrict__ bz,
    float* __restrict__ out) {
  __shared__ char lds[98304];  // 64KB A + 32KB B
  const int bid = blockIdx.x;
  const int sid = (bid & 7) * 64 + (bid >> 3);  // 512 % 8 == 0
  const int bm = sid >> 3, bn = sid & 7;
  f32x4 acc[8][2];
#pragma unroll
  for (int m = 0; m < 8; ++m)
#pragma unroll
    for (int n = 0; n < 2; ++n) acc[m][n] = (f32x4)(0.0f);

  // A: kt<32 -> Znb (stride 1024), kt>=32 -> x half of U (stride 2048)
  gemm_core<2, 32, false>(Zn, HDIM, U, K1, Wzcat, (long)bm * 256, (long)bn * 128, lds, acc);

  const int t = threadIdx.x, lane = t & 63, wv = t >> 6;
  const int wm = wv >> 2, wn = wv & 3;
  const int rA = lane & 15, q4 = (lane >> 4) << 2;
  const int rowbase = bm * 256 + wm * 128;
#pragma unroll
  for (int n = 0; n < 2; ++n) {
    const int hc = bn * 128 + wn * 32 + n * 16 + rA;
    const float bzv = bz[hc];
#pragma unroll
    for (int m = 0; m < 8; ++m) {
#pragma unroll
      for (int j = 0; j < 4; ++j) {
        const int b = rowbase + m * 16 + q4 + j;
        const long idx = (long)b * HDIM + hc;
        const float tv = tanhf_(acc[m][n][j] + bzv);
        const float sb = bf2f(sbb[idx]);
        out[idx] = (1.0f - sb) * yin[idx] + sb * tv;  // y_new
      }
    }
  }
}

extern "C" void kernel_launch(void* const* d_in, const int* in_sizes, int n_in,
                              void* d_out, int out_size, void* d_ws, size_t ws_size,
                              hipStream_t stream) {
  const float* x   = (const float*)d_in[0];
  const float* y   = (const float*)d_in[1];
  const float* z   = (const float*)d_in[2];
  const float* dtp = (const float*)d_in[3];
  const float* Wih = (const float*)d_in[4];
  const float* bih = (const float*)d_in[5];
  const float* Whh = (const float*)d_in[6];
  const float* bhh = (const float*)d_in[7];
  const float* Wz  = (const float*)d_in[8];
  const float* bz  = (const float*)d_in[9];
  const float* Wdt = (const float*)d_in[10];
  const float* bdt = (const float*)d_in[11];

  char* ws = (char*)d_ws;
  unsigned short* U     = (unsigned short*)(ws);              // 67,108,864 B
  unsigned short* Wcat  = (unsigned short*)(ws + 67108864);   // 12,582,912 B
  unsigned short* Wzcat = (unsigned short*)(ws + 79691776);   //  4,194,304 B
  unsigned short* Znb   = (unsigned short*)(ws + 83886080);   // 33,554,432 B
  unsigned short* Sbb   = (unsigned short*)(ws + 117440512);  // 33,554,432 B -> 150,994,944 B
  float* out = (float*)d_out;

  k_convU<<<2048, 256, 0, stream>>>(x, y, U);
  k_convW<<<2048, 256, 0, stream>>>(Wih, Whh, Wz, Wcat, Wzcat);
  k_gemm1<<<1024, 512, 0, stream>>>(U, Wcat, z, dtp, bih, bhh, Wdt, bdt, out, Znb, Sbb);
  k_gemm2<<<512, 512, 0, stream>>>(Znb, U, Wzcat, Sbb, y, bz, out);
}